// Round 10
// baseline (90.355 us; speedup 1.0000x reference)
//
#include <hip/hip_runtime.h>
#include <math.h>

// Problem constants
#define BB   64
#define LL   4096
#define DKC  128
#define DVC  128
#define HC   4
#define DKLC 64
#define DVLC 128
#define RC   128

#define NCA  64            // chunks per batch (64-row blocks)
#define CA   64            // rows per chunk

// Nontemporal float4 load: V only (streamed, never cached -> can't evict K).
// K/mask use NORMAL cached loads: 158 MB working set fits 256 MB L3 and
// becomes L3-resident across graph replays (cross-replay reuse).
typedef float f4v __attribute__((ext_vector_type(4)));
__device__ __forceinline__ float4 ntload4(const float4* p) {
    f4v v = __builtin_nontemporal_load((const f4v*)p);
    return make_float4(v.x, v.y, v.z, v.w);
}
__device__ __forceinline__ float dot4(float4 a, float4 b) {
    return a.x * b.x + a.y * b.y + a.z * b.z + a.w * b.w;
}

// ---------------------------------------------------------------------------
// Kernel 0: fold q[h][d] = sum_k Wq[h,k] * Wk[d,h,k]   (H*DK = 512 values)
// ---------------------------------------------------------------------------
__global__ __launch_bounds__(512) void k_foldq(const float* __restrict__ Wq,
                                               const float* __restrict__ Wk,
                                               float* __restrict__ q) {
    int t = threadIdx.x;            // 0..511
    int h = t >> 7;                 // 0..3
    int d = t & 127;                // 0..127
    float acc = 0.f;
#pragma unroll 8
    for (int k = 0; k < DKLC; ++k)
        acc += Wq[h * DKLC + k] * Wk[(d * HC + h) * DKLC + k];
    q[h * DKC + d] = acc;
}

// ---------------------------------------------------------------------------
// Wave-private fused kernel (round-8 structure, K/mask now CACHED loads).
// Block = (b, 64-row chunk); wave w owns rows [w*16, w*16+16).
// ---------------------------------------------------------------------------
__global__ __launch_bounds__(256) void k_fused(const float* __restrict__ K,
                                               const float* __restrict__ V,
                                               const int*   __restrict__ mask,
                                               const float* __restrict__ q,
                                               float* __restrict__ stats,
                                               float* __restrict__ partWV) {
    const int bid = blockIdx.x;            // b*NCA + a
    const int b   = bid >> 6;
    const int a   = bid & (NCA - 1);
    const int l0  = a * CA;
    const int t   = threadIdx.x;
    const int w   = t >> 6;                // wave id
    const int ln  = t & 63;
    const int lin = ln & 15;               // lane-in-row (score stage)
    const int rh  = ln >> 5;               // row-half (PV stage)
    const int rowbase = l0 + w * 16;       // wave's first row (within batch b)

    const float4* Kb = (const float4*)(K + (long)b * LL * DKC);
    const float4* Vb = (const float4*)(V + (long)b * LL * DVC);

    // ---- issue ALL loads up front (16 x 1KB per wave, independent) ----
    // K: cached (L3-resident across replays). V: NT (stream, no allocation).
    float4 k0[4], k1[4];
#pragma unroll
    for (int p = 0; p < 4; ++p) {
        int rp = rowbase + p * 4 + (ln >> 4);
        k0[p] = Kb[rp * 32 + lin];                  // 4 rows x 256 B
        k1[p] = Kb[rp * 32 + 16 + lin];             // 4 rows x 256 B
    }
    float4 vv[8];
#pragma unroll
    for (int it = 0; it < 8; ++it) {
        int rv = rowbase + it * 2 + rh;
        vv[it] = ntload4(&Vb[rv * 32 + (ln & 31)]); // 2 rows x 512 B
    }
    int mk[4];
#pragma unroll
    for (int p = 0; p < 4; ++p)
        mk[p] = mask[(long)b * LL + rowbase + p * 4 + (ln >> 4)];

    // folded q fragments (cached loads, tiny)
    float4 qa[HC], qb[HC];
#pragma unroll
    for (int h = 0; h < HC; ++h) {
        qa[h] = ((const float4*)q)[h * 32 + lin];
        qb[h] = ((const float4*)q)[h * 32 + 16 + lin];
    }

    // ---- score passes: 4 rows each, 16 lanes per row ----
    const float scale = 0.08838834764831844f;   // 1/sqrt(128)
    float4 d[4];
#pragma unroll
    for (int p = 0; p < 4; ++p) {
        float4 dd;
        dd.x = dot4(k0[p], qa[0]) + dot4(k1[p], qb[0]);
        dd.y = dot4(k0[p], qa[1]) + dot4(k1[p], qb[1]);
        dd.z = dot4(k0[p], qa[2]) + dot4(k1[p], qb[2]);
        dd.w = dot4(k0[p], qa[3]) + dot4(k1[p], qb[3]);
#pragma unroll
        for (int off = 1; off <= 8; off <<= 1) {
            dd.x += __shfl_xor(dd.x, off);
            dd.y += __shfl_xor(dd.y, off);
            dd.z += __shfl_xor(dd.z, off);
            dd.w += __shfl_xor(dd.w, off);
        }
        d[p].x = mk[p] ? -INFINITY : dd.x * scale;
        d[p].y = mk[p] ? -INFINITY : dd.y * scale;
        d[p].z = mk[p] ? -INFINITY : dd.z * scale;
        d[p].w = mk[p] ? -INFINITY : dd.w * scale;
    }

    // ---- per-head max over the wave's 16 rows ----
    float4 m4;
    m4.x = fmaxf(fmaxf(d[0].x, d[1].x), fmaxf(d[2].x, d[3].x));
    m4.y = fmaxf(fmaxf(d[0].y, d[1].y), fmaxf(d[2].y, d[3].y));
    m4.z = fmaxf(fmaxf(d[0].z, d[1].z), fmaxf(d[2].z, d[3].z));
    m4.w = fmaxf(fmaxf(d[0].w, d[1].w), fmaxf(d[2].w, d[3].w));
#pragma unroll
    for (int off = 16; off <= 32; off <<= 1) {
        m4.x = fmaxf(m4.x, __shfl_xor(m4.x, off));
        m4.y = fmaxf(m4.y, __shfl_xor(m4.y, off));
        m4.z = fmaxf(m4.z, __shfl_xor(m4.z, off));
        m4.w = fmaxf(m4.w, __shfl_xor(m4.w, off));
    }
    float4 mu4;
    mu4.x = (m4.x == -INFINITY) ? 0.f : m4.x;   // all-masked guard
    mu4.y = (m4.y == -INFINITY) ? 0.f : m4.y;
    mu4.z = (m4.z == -INFINITY) ? 0.f : m4.z;
    mu4.w = (m4.w == -INFINITY) ? 0.f : m4.w;

    // ---- P = exp(s - mu) (replicated across the 16-lane group) + Z ----
    float4 pp[4];
#pragma unroll
    for (int p = 0; p < 4; ++p) {
        pp[p].x = expf(d[p].x - mu4.x);
        pp[p].y = expf(d[p].y - mu4.y);
        pp[p].z = expf(d[p].z - mu4.z);
        pp[p].w = expf(d[p].w - mu4.w);
    }
    float4 z4;
    z4.x = pp[0].x + pp[1].x + pp[2].x + pp[3].x;
    z4.y = pp[0].y + pp[1].y + pp[2].y + pp[3].y;
    z4.z = pp[0].z + pp[1].z + pp[2].z + pp[3].z;
    z4.w = pp[0].w + pp[1].w + pp[2].w + pp[3].w;
#pragma unroll
    for (int off = 16; off <= 32; off <<= 1) {
        z4.x += __shfl_xor(z4.x, off);
        z4.y += __shfl_xor(z4.y, off);
        z4.z += __shfl_xor(z4.z, off);
        z4.w += __shfl_xor(z4.w, off);
    }

    // ---- PV: route P to (row-half, col) layout via static-index shfl ----
    float4 acc[HC];
#pragma unroll
    for (int h = 0; h < HC; ++h) acc[h] = make_float4(0.f, 0.f, 0.f, 0.f);
#pragma unroll
    for (int it = 0; it < 8; ++it) {
        int src = (((2 * it) & 3) + rh) * 16 + lin;   // group holding row it*2+rh
        float4 w4;
        w4.x = __shfl(pp[it >> 1].x, src);
        w4.y = __shfl(pp[it >> 1].y, src);
        w4.z = __shfl(pp[it >> 1].z, src);
        w4.w = __shfl(pp[it >> 1].w, src);
        float4 v = vv[it];
        acc[0].x += w4.x*v.x; acc[0].y += w4.x*v.y; acc[0].z += w4.x*v.z; acc[0].w += w4.x*v.w;
        acc[1].x += w4.y*v.x; acc[1].y += w4.y*v.y; acc[1].z += w4.y*v.z; acc[1].w += w4.y*v.w;
        acc[2].x += w4.z*v.x; acc[2].y += w4.z*v.y; acc[2].z += w4.z*v.z; acc[2].w += w4.z*v.w;
        acc[3].x += w4.w*v.x; acc[3].y += w4.w*v.y; acc[3].z += w4.w*v.z; acc[3].w += w4.w*v.w;
    }

    // ---- block-end combine (the ONLY barriers) ----
    __shared__ float4 wsm[4], wsz[4];
    __shared__ float4 red[4][32][HC];      // 8 KB
    if (ln == 0) { wsm[w] = m4; wsz[w] = z4; }
    __syncthreads();

    float4 mb;
    mb.x = fmaxf(fmaxf(wsm[0].x, wsm[1].x), fmaxf(wsm[2].x, wsm[3].x));
    mb.y = fmaxf(fmaxf(wsm[0].y, wsm[1].y), fmaxf(wsm[2].y, wsm[3].y));
    mb.z = fmaxf(fmaxf(wsm[0].z, wsm[1].z), fmaxf(wsm[2].z, wsm[3].z));
    mb.w = fmaxf(fmaxf(wsm[0].w, wsm[1].w), fmaxf(wsm[2].w, wsm[3].w));
    float4 mub;
    mub.x = (mb.x == -INFINITY) ? 0.f : mb.x;
    mub.y = (mb.y == -INFINITY) ? 0.f : mb.y;
    mub.z = (mb.z == -INFINITY) ? 0.f : mb.z;
    mub.w = (mb.w == -INFINITY) ? 0.f : mb.w;
    // this wave's rescale factor to block max
    float4 fw;
    fw.x = (wsm[w].x == -INFINITY) ? 0.f : expf(wsm[w].x - mub.x);
    fw.y = (wsm[w].y == -INFINITY) ? 0.f : expf(wsm[w].y - mub.y);
    fw.z = (wsm[w].z == -INFINITY) ? 0.f : expf(wsm[w].z - mub.z);
    fw.w = (wsm[w].w == -INFINITY) ? 0.f : expf(wsm[w].w - mub.w);
    acc[0].x *= fw.x; acc[0].y *= fw.x; acc[0].z *= fw.x; acc[0].w *= fw.x;
    acc[1].x *= fw.y; acc[1].y *= fw.y; acc[1].z *= fw.y; acc[1].w *= fw.y;
    acc[2].x *= fw.z; acc[2].y *= fw.z; acc[2].z *= fw.z; acc[2].w *= fw.z;
    acc[3].x *= fw.w; acc[3].y *= fw.w; acc[3].z *= fw.w; acc[3].w *= fw.w;

    // pair-combine the two row-halves (lane ^ 32)
#pragma unroll
    for (int h = 0; h < HC; ++h) {
        acc[h].x += __shfl_xor(acc[h].x, 32);
        acc[h].y += __shfl_xor(acc[h].y, 32);
        acc[h].z += __shfl_xor(acc[h].z, 32);
        acc[h].w += __shfl_xor(acc[h].w, 32);
    }
    if (ln < 32) {
#pragma unroll
        for (int h = 0; h < HC; ++h) red[w][ln][h] = acc[h];
    }
    if (t == 0) {
        stats[(long)bid * 8 + 0] = mb.x;
        stats[(long)bid * 8 + 1] = mb.y;
        stats[(long)bid * 8 + 2] = mb.z;
        stats[(long)bid * 8 + 3] = mb.w;
        float zx = 0.f, zy = 0.f, zz = 0.f, zw = 0.f;
#pragma unroll
        for (int w2 = 0; w2 < 4; ++w2) {
            zx += ((wsm[w2].x == -INFINITY) ? 0.f : expf(wsm[w2].x - mub.x)) * wsz[w2].x;
            zy += ((wsm[w2].y == -INFINITY) ? 0.f : expf(wsm[w2].y - mub.y)) * wsz[w2].y;
            zz += ((wsm[w2].z == -INFINITY) ? 0.f : expf(wsm[w2].z - mub.z)) * wsz[w2].z;
            zw += ((wsm[w2].w == -INFINITY) ? 0.f : expf(wsm[w2].w - mub.w)) * wsz[w2].w;
        }
        stats[(long)bid * 8 + 4] = zx;
        stats[(long)bid * 8 + 5] = zy;
        stats[(long)bid * 8 + 6] = zz;
        stats[(long)bid * 8 + 7] = zw;
    }
    __syncthreads();
    if (t < 128) {
        int h = t >> 5, c = t & 31;
        float4 s0 = red[0][c][h], s1 = red[1][c][h];
        float4 s2 = red[2][c][h], s3 = red[3][c][h];
        float4 o;
        o.x = s0.x + s1.x + s2.x + s3.x;
        o.y = s0.y + s1.y + s2.y + s3.y;
        o.z = s0.z + s1.z + s2.z + s3.z;
        o.w = s0.w + s1.w + s2.w + s3.w;
        ((float4*)partWV)[((long)bid * HC + h) * (DVC / 4) + c] = o;
    }
}

// ---------------------------------------------------------------------------
// Epilogue: combine 64 chunk-partials per b (wave = head, lane = chunk),
// then QKV = (1/L) WV*Wv ; out = QKV*Wo.   One block per b.
// ---------------------------------------------------------------------------
__global__ __launch_bounds__(256) void k_out(const float* __restrict__ stats,
                                             const float* __restrict__ partWV,
                                             const float* __restrict__ Wv,
                                             const float* __restrict__ Wo,
                                             float* __restrict__ out) {
    int b = blockIdx.x;
    int t = threadIdx.x;
    __shared__ float WV[HC][DVC];        // 2 KB
    __shared__ float QKV[HC * DVLC];     // 2 KB
    __shared__ float sc[NCA][HC];        // 1 KB rescale factors
    __shared__ float zinv[HC];

    // wave h2 = head, lane a = chunk (NCA = 64 = wave width)
    {
        int h2 = t >> 6, a = t & 63;
        float ma = stats[((long)b * NCA + a) * 8 + h2];
        float za = stats[((long)b * NCA + a) * 8 + 4 + h2];
        float m = ma;
#pragma unroll
        for (int off = 32; off; off >>= 1) m = fmaxf(m, __shfl_xor(m, off));
        // l=0 is never masked -> m finite, Z > 0
        float f  = (ma == -INFINITY) ? 0.f : expf(ma - m);
        sc[a][h2] = f;
        float fz = f * za;
#pragma unroll
        for (int off = 32; off; off >>= 1) fz += __shfl_xor(fz, off);
        if (a == 0) zinv[h2] = 1.0f / fz;
    }
    __syncthreads();

    for (int j = t; j < HC * DVC; j += 256) {
        int h = j >> 7, e = j & 127;
        float acc = 0.f;
#pragma unroll 8
        for (int p = 0; p < NCA; ++p)
            acc += sc[p][h] * partWV[(((long)b * NCA + p) * HC + h) * DVC + e];
        WV[h][e] = acc * zinv[h];
    }
    __syncthreads();

    for (int j = t; j < HC * DVLC; j += 256) {
        int h = j >> 7, vv = j & 127;
        float acc = 0.f;
#pragma unroll 8
        for (int e = 0; e < DVC; ++e)
            acc += WV[h][e] * Wv[(e * HC + h) * DVLC + vv];
        QKV[j] = acc * (1.0f / LL);
    }
    __syncthreads();

    for (int r = t; r < RC; r += 256) {
        float acc = 0.f;
#pragma unroll 8
        for (int i = 0; i < HC * DVLC; ++i)
            acc += QKV[i] * Wo[i * RC + r];
        out[b * RC + r] = acc;
    }
}

// ---------------------------------------------------------------------------
extern "C" void kernel_launch(void* const* d_in, const int* in_sizes, int n_in,
                              void* d_out, int out_size, void* d_ws, size_t ws_size,
                              hipStream_t stream) {
    (void)in_sizes; (void)n_in; (void)out_size; (void)ws_size;
    const float* K    = (const float*)d_in[0];
    const float* V    = (const float*)d_in[1];
    const int*   mask = (const int*)  d_in[2];
    const float* Wq   = (const float*)d_in[3];
    const float* Wk   = (const float*)d_in[4];
    const float* Wv   = (const float*)d_in[5];
    const float* Wo   = (const float*)d_in[6];
    float* out = (float*)d_out;

    float* q      = (float*)d_ws;                         // 512
    float* stats  = q + 512;                              // B*NCA*8   = 32768
    float* partWV = stats + (long)BB * NCA * 8;           // B*NCA*H*DV = 2M floats

    k_foldq<<<1, 512, 0, stream>>>(Wq, Wk, q);
    k_fused<<<BB * NCA, 256, 0, stream>>>(K, V, mask, q, stats, partWV);
    k_out<<<BB, 256, 0, stream>>>(stats, partWV, Wv, Wo, out);
}

// Round 11
// 77.625 us; speedup vs baseline: 1.1640x; 1.1640x over previous
//
#include <hip/hip_runtime.h>
#include <math.h>

// Problem constants
#define BB   64
#define LL   4096
#define DKC  128
#define DVC  128
#define HC   4
#define DKLC 64
#define DVLC 128
#define RC   128

#define NCA  64            // chunks per batch (64-row blocks)
#define CA   64            // rows per chunk

// Nontemporal float4 load (bypass cache allocation for streamed-once data).
// Measured on this problem (rounds 6-10): NT beats cached for ALL streams,
// including L3-resident ones (R10: cached-K hit L3 yet ran 11 us slower).
typedef float f4v __attribute__((ext_vector_type(4)));
__device__ __forceinline__ float4 ntload4(const float4* p) {
    f4v v = __builtin_nontemporal_load((const f4v*)p);
    return make_float4(v.x, v.y, v.z, v.w);
}
__device__ __forceinline__ float dot4(float4 a, float4 b) {
    return a.x * b.x + a.y * b.y + a.z * b.z + a.w * b.w;
}

// ---------------------------------------------------------------------------
// Kernel 0: fold q[h][d] = sum_k Wq[h,k] * Wk[d,h,k]   (H*DK = 512 values)
// ---------------------------------------------------------------------------
__global__ __launch_bounds__(512) void k_foldq(const float* __restrict__ Wq,
                                               const float* __restrict__ Wk,
                                               float* __restrict__ q) {
    int t = threadIdx.x;            // 0..511
    int h = t >> 7;                 // 0..3
    int d = t & 127;                // 0..127
    float acc = 0.f;
#pragma unroll 8
    for (int k = 0; k < DKLC; ++k)
        acc += Wq[h * DKLC + k] * Wk[(d * HC + h) * DKLC + k];
    q[h * DKC + d] = acc;
}

// ---------------------------------------------------------------------------
// Wave-private fused kernel. Block = (b, 64-row chunk); wave w owns rows
// [w*16, w*16+16). NO __syncthreads between first load and block-end combine:
//  - issue all 8 K + 8 V NT loads up front (per wave, independent)
//  - score pass p (4 rows x 16 lanes): dot partials + shfl_xor{1,2,4,8}
//  - per-head softmax stats over 16 rows: shfl_xor{16,32}; P in registers
//  - PV: P routed by 32 static-index __shfl gathers; FMA with V registers
//  - block-end: 2 barriers; waves' partials max-rescaled and combined
// ---------------------------------------------------------------------------
__global__ __launch_bounds__(256) void k_fused(const float* __restrict__ K,
                                               const float* __restrict__ V,
                                               const int*   __restrict__ mask,
                                               const float* __restrict__ q,
                                               float* __restrict__ stats,
                                               float* __restrict__ partWV) {
    const int bid = blockIdx.x;            // b*NCA + a
    const int b   = bid >> 6;
    const int a   = bid & (NCA - 1);
    const int l0  = a * CA;
    const int t   = threadIdx.x;
    const int w   = t >> 6;                // wave id
    const int ln  = t & 63;
    const int lin = ln & 15;               // lane-in-row (score stage)
    const int rh  = ln >> 5;               // row-half (PV stage)
    const int rowbase = l0 + w * 16;       // wave's first row (within batch b)

    const float4* Kb = (const float4*)(K + (long)b * LL * DKC);
    const float4* Vb = (const float4*)(V + (long)b * LL * DVC);

    // ---- issue ALL NT loads up front (16 x 1KB per wave, independent) ----
    float4 k0[4], k1[4];
#pragma unroll
    for (int p = 0; p < 4; ++p) {
        int rp = rowbase + p * 4 + (ln >> 4);
        k0[p] = ntload4(&Kb[rp * 32 + lin]);        // 4 rows x 256 B
        k1[p] = ntload4(&Kb[rp * 32 + 16 + lin]);   // 4 rows x 256 B
    }
    float4 vv[8];
#pragma unroll
    for (int it = 0; it < 8; ++it) {
        int rv = rowbase + it * 2 + rh;
        vv[it] = ntload4(&Vb[rv * 32 + (ln & 31)]); // 2 rows x 512 B
    }
    int mk[4];
#pragma unroll
    for (int p = 0; p < 4; ++p)
        mk[p] = __builtin_nontemporal_load(mask + (long)b * LL + rowbase + p * 4 + (ln >> 4));

    // folded q fragments (cached loads, tiny)
    float4 qa[HC], qb[HC];
#pragma unroll
    for (int h = 0; h < HC; ++h) {
        qa[h] = ((const float4*)q)[h * 32 + lin];
        qb[h] = ((const float4*)q)[h * 32 + 16 + lin];
    }

    // ---- score passes: 4 rows each, 16 lanes per row ----
    const float scale = 0.08838834764831844f;   // 1/sqrt(128)
    float4 d[4];
#pragma unroll
    for (int p = 0; p < 4; ++p) {
        float4 dd;
        dd.x = dot4(k0[p], qa[0]) + dot4(k1[p], qb[0]);
        dd.y = dot4(k0[p], qa[1]) + dot4(k1[p], qb[1]);
        dd.z = dot4(k0[p], qa[2]) + dot4(k1[p], qb[2]);
        dd.w = dot4(k0[p], qa[3]) + dot4(k1[p], qb[3]);
#pragma unroll
        for (int off = 1; off <= 8; off <<= 1) {
            dd.x += __shfl_xor(dd.x, off);
            dd.y += __shfl_xor(dd.y, off);
            dd.z += __shfl_xor(dd.z, off);
            dd.w += __shfl_xor(dd.w, off);
        }
        d[p].x = mk[p] ? -INFINITY : dd.x * scale;
        d[p].y = mk[p] ? -INFINITY : dd.y * scale;
        d[p].z = mk[p] ? -INFINITY : dd.z * scale;
        d[p].w = mk[p] ? -INFINITY : dd.w * scale;
    }

    // ---- per-head max over the wave's 16 rows ----
    float4 m4;
    m4.x = fmaxf(fmaxf(d[0].x, d[1].x), fmaxf(d[2].x, d[3].x));
    m4.y = fmaxf(fmaxf(d[0].y, d[1].y), fmaxf(d[2].y, d[3].y));
    m4.z = fmaxf(fmaxf(d[0].z, d[1].z), fmaxf(d[2].z, d[3].z));
    m4.w = fmaxf(fmaxf(d[0].w, d[1].w), fmaxf(d[2].w, d[3].w));
#pragma unroll
    for (int off = 16; off <= 32; off <<= 1) {
        m4.x = fmaxf(m4.x, __shfl_xor(m4.x, off));
        m4.y = fmaxf(m4.y, __shfl_xor(m4.y, off));
        m4.z = fmaxf(m4.z, __shfl_xor(m4.z, off));
        m4.w = fmaxf(m4.w, __shfl_xor(m4.w, off));
    }
    float4 mu4;
    mu4.x = (m4.x == -INFINITY) ? 0.f : m4.x;   // all-masked guard
    mu4.y = (m4.y == -INFINITY) ? 0.f : m4.y;
    mu4.z = (m4.z == -INFINITY) ? 0.f : m4.z;
    mu4.w = (m4.w == -INFINITY) ? 0.f : m4.w;

    // ---- P = exp(s - mu) (replicated across the 16-lane group) + Z ----
    float4 pp[4];
#pragma unroll
    for (int p = 0; p < 4; ++p) {
        pp[p].x = expf(d[p].x - mu4.x);
        pp[p].y = expf(d[p].y - mu4.y);
        pp[p].z = expf(d[p].z - mu4.z);
        pp[p].w = expf(d[p].w - mu4.w);
    }
    float4 z4;
    z4.x = pp[0].x + pp[1].x + pp[2].x + pp[3].x;
    z4.y = pp[0].y + pp[1].y + pp[2].y + pp[3].y;
    z4.z = pp[0].z + pp[1].z + pp[2].z + pp[3].z;
    z4.w = pp[0].w + pp[1].w + pp[2].w + pp[3].w;
#pragma unroll
    for (int off = 16; off <= 32; off <<= 1) {
        z4.x += __shfl_xor(z4.x, off);
        z4.y += __shfl_xor(z4.y, off);
        z4.z += __shfl_xor(z4.z, off);
        z4.w += __shfl_xor(z4.w, off);
    }

    // ---- PV: route P to (row-half, col) layout via static-index shfl ----
    float4 acc[HC];
#pragma unroll
    for (int h = 0; h < HC; ++h) acc[h] = make_float4(0.f, 0.f, 0.f, 0.f);
#pragma unroll
    for (int it = 0; it < 8; ++it) {
        int src = (((2 * it) & 3) + rh) * 16 + lin;   // group holding row it*2+rh
        float4 w4;
        w4.x = __shfl(pp[it >> 1].x, src);
        w4.y = __shfl(pp[it >> 1].y, src);
        w4.z = __shfl(pp[it >> 1].z, src);
        w4.w = __shfl(pp[it >> 1].w, src);
        float4 v = vv[it];
        acc[0].x += w4.x*v.x; acc[0].y += w4.x*v.y; acc[0].z += w4.x*v.z; acc[0].w += w4.x*v.w;
        acc[1].x += w4.y*v.x; acc[1].y += w4.y*v.y; acc[1].z += w4.y*v.z; acc[1].w += w4.y*v.w;
        acc[2].x += w4.z*v.x; acc[2].y += w4.z*v.y; acc[2].z += w4.z*v.z; acc[2].w += w4.z*v.w;
        acc[3].x += w4.w*v.x; acc[3].y += w4.w*v.y; acc[3].z += w4.w*v.z; acc[3].w += w4.w*v.w;
    }

    // ---- block-end combine (the ONLY barriers) ----
    __shared__ float4 wsm[4], wsz[4];
    __shared__ float4 red[4][32][HC];      // 8 KB
    if (ln == 0) { wsm[w] = m4; wsz[w] = z4; }
    __syncthreads();

    float4 mb;
    mb.x = fmaxf(fmaxf(wsm[0].x, wsm[1].x), fmaxf(wsm[2].x, wsm[3].x));
    mb.y = fmaxf(fmaxf(wsm[0].y, wsm[1].y), fmaxf(wsm[2].y, wsm[3].y));
    mb.z = fmaxf(fmaxf(wsm[0].z, wsm[1].z), fmaxf(wsm[2].z, wsm[3].z));
    mb.w = fmaxf(fmaxf(wsm[0].w, wsm[1].w), fmaxf(wsm[2].w, wsm[3].w));
    float4 mub;
    mub.x = (mb.x == -INFINITY) ? 0.f : mb.x;
    mub.y = (mb.y == -INFINITY) ? 0.f : mb.y;
    mub.z = (mb.z == -INFINITY) ? 0.f : mb.z;
    mub.w = (mb.w == -INFINITY) ? 0.f : mb.w;
    // this wave's rescale factor to block max
    float4 fw;
    fw.x = (wsm[w].x == -INFINITY) ? 0.f : expf(wsm[w].x - mub.x);
    fw.y = (wsm[w].y == -INFINITY) ? 0.f : expf(wsm[w].y - mub.y);
    fw.z = (wsm[w].z == -INFINITY) ? 0.f : expf(wsm[w].z - mub.z);
    fw.w = (wsm[w].w == -INFINITY) ? 0.f : expf(wsm[w].w - mub.w);
    acc[0].x *= fw.x; acc[0].y *= fw.x; acc[0].z *= fw.x; acc[0].w *= fw.x;
    acc[1].x *= fw.y; acc[1].y *= fw.y; acc[1].z *= fw.y; acc[1].w *= fw.y;
    acc[2].x *= fw.z; acc[2].y *= fw.z; acc[2].z *= fw.z; acc[2].w *= fw.z;
    acc[3].x *= fw.w; acc[3].y *= fw.w; acc[3].z *= fw.w; acc[3].w *= fw.w;

    // pair-combine the two row-halves (lane ^ 32)
#pragma unroll
    for (int h = 0; h < HC; ++h) {
        acc[h].x += __shfl_xor(acc[h].x, 32);
        acc[h].y += __shfl_xor(acc[h].y, 32);
        acc[h].z += __shfl_xor(acc[h].z, 32);
        acc[h].w += __shfl_xor(acc[h].w, 32);
    }
    if (ln < 32) {
#pragma unroll
        for (int h = 0; h < HC; ++h) red[w][ln][h] = acc[h];
    }
    if (t == 0) {
        stats[(long)bid * 8 + 0] = mb.x;
        stats[(long)bid * 8 + 1] = mb.y;
        stats[(long)bid * 8 + 2] = mb.z;
        stats[(long)bid * 8 + 3] = mb.w;
        float zx = 0.f, zy = 0.f, zz = 0.f, zw = 0.f;
#pragma unroll
        for (int w2 = 0; w2 < 4; ++w2) {
            zx += ((wsm[w2].x == -INFINITY) ? 0.f : expf(wsm[w2].x - mub.x)) * wsz[w2].x;
            zy += ((wsm[w2].y == -INFINITY) ? 0.f : expf(wsm[w2].y - mub.y)) * wsz[w2].y;
            zz += ((wsm[w2].z == -INFINITY) ? 0.f : expf(wsm[w2].z - mub.z)) * wsz[w2].z;
            zw += ((wsm[w2].w == -INFINITY) ? 0.f : expf(wsm[w2].w - mub.w)) * wsz[w2].w;
        }
        stats[(long)bid * 8 + 4] = zx;
        stats[(long)bid * 8 + 5] = zy;
        stats[(long)bid * 8 + 6] = zz;
        stats[(long)bid * 8 + 7] = zw;
    }
    __syncthreads();
    if (t < 128) {
        int h = t >> 5, c = t & 31;
        float4 s0 = red[0][c][h], s1 = red[1][c][h];
        float4 s2 = red[2][c][h], s3 = red[3][c][h];
        float4 o;
        o.x = s0.x + s1.x + s2.x + s3.x;
        o.y = s0.y + s1.y + s2.y + s3.y;
        o.z = s0.z + s1.z + s2.z + s3.z;
        o.w = s0.w + s1.w + s2.w + s3.w;
        ((float4*)partWV)[((long)bid * HC + h) * (DVC / 4) + c] = o;
    }
}

// ---------------------------------------------------------------------------
// Epilogue: combine 64 chunk-partials per b (wave = head, lane = chunk),
// then QKV = (1/L) WV*Wv ; out = QKV*Wo.   One block per b.
// ---------------------------------------------------------------------------
__global__ __launch_bounds__(256) void k_out(const float* __restrict__ stats,
                                             const float* __restrict__ partWV,
                                             const float* __restrict__ Wv,
                                             const float* __restrict__ Wo,
                                             float* __restrict__ out) {
    int b = blockIdx.x;
    int t = threadIdx.x;
    __shared__ float WV[HC][DVC];        // 2 KB
    __shared__ float QKV[HC * DVLC];     // 2 KB
    __shared__ float sc[NCA][HC];        // 1 KB rescale factors
    __shared__ float zinv[HC];

    // wave h2 = head, lane a = chunk (NCA = 64 = wave width)
    {
        int h2 = t >> 6, a = t & 63;
        float ma = stats[((long)b * NCA + a) * 8 + h2];
        float za = stats[((long)b * NCA + a) * 8 + 4 + h2];
        float m = ma;
#pragma unroll
        for (int off = 32; off; off >>= 1) m = fmaxf(m, __shfl_xor(m, off));
        // l=0 is never masked -> m finite, Z > 0
        float f  = (ma == -INFINITY) ? 0.f : expf(ma - m);
        sc[a][h2] = f;
        float fz = f * za;
#pragma unroll
        for (int off = 32; off; off >>= 1) fz += __shfl_xor(fz, off);
        if (a == 0) zinv[h2] = 1.0f / fz;
    }
    __syncthreads();

    for (int j = t; j < HC * DVC; j += 256) {
        int h = j >> 7, e = j & 127;
        float acc = 0.f;
#pragma unroll 8
        for (int p = 0; p < NCA; ++p)
            acc += sc[p][h] * partWV[(((long)b * NCA + p) * HC + h) * DVC + e];
        WV[h][e] = acc * zinv[h];
    }
    __syncthreads();

    for (int j = t; j < HC * DVLC; j += 256) {
        int h = j >> 7, vv = j & 127;
        float acc = 0.f;
#pragma unroll 8
        for (int e = 0; e < DVC; ++e)
            acc += WV[h][e] * Wv[(e * HC + h) * DVLC + vv];
        QKV[j] = acc * (1.0f / LL);
    }
    __syncthreads();

    for (int r = t; r < RC; r += 256) {
        float acc = 0.f;
#pragma unroll 8
        for (int i = 0; i < HC * DVLC; ++i)
            acc += QKV[i] * Wo[i * RC + r];
        out[b * RC + r] = acc;
    }
}

// ---------------------------------------------------------------------------
extern "C" void kernel_launch(void* const* d_in, const int* in_sizes, int n_in,
                              void* d_out, int out_size, void* d_ws, size_t ws_size,
                              hipStream_t stream) {
    (void)in_sizes; (void)n_in; (void)out_size; (void)ws_size;
    const float* K    = (const float*)d_in[0];
    const float* V    = (const float*)d_in[1];
    const int*   mask = (const int*)  d_in[2];
    const float* Wq   = (const float*)d_in[3];
    const float* Wk   = (const float*)d_in[4];
    const float* Wv   = (const float*)d_in[5];
    const float* Wo   = (const float*)d_in[6];
    float* out = (float*)d_out;

    float* q      = (float*)d_ws;                         // 512
    float* stats  = q + 512;                              // B*NCA*8   = 32768
    float* partWV = stats + (long)BB * NCA * 8;           // B*NCA*H*DV = 2M floats

    k_foldq<<<1, 512, 0, stream>>>(Wq, Wk, q);
    k_fused<<<BB * NCA, 256, 0, stream>>>(K, V, mask, q, stats, partWV);
    k_out<<<BB, 256, 0, stream>>>(stats, partWV, Wv, Wo, out);
}